// Round 3
// baseline (2536.487 us; speedup 1.0000x reference)
//
#include <hip/hip_runtime.h>

#define B_   4
#define NB_  128
#define BS_  128
#define C_   256
#define H_   8
#define KL_  129   // BS_+1
#define SCALE_ 0.17677669529663687f

typedef unsigned short u16;
typedef unsigned int   u32;
typedef short          s16;
typedef __attribute__((ext_vector_type(8))) __bf16 bf16x8;
typedef __attribute__((ext_vector_type(4))) float  f32x4;

__device__ __forceinline__ float bf16tof(u16 u) {
  union { u32 i; float f; } v; v.i = ((u32)u) << 16; return v.f;
}
__device__ __forceinline__ u16 ftobf16(float f) {
  union { float f; u32 i; } v; v.f = f;
  u32 b = v.i + 0x7FFFu + ((v.i >> 16) & 1u);
  return (u16)(b >> 16);
}
__device__ __forceinline__ void unpack8(uint4 u, float* d) {
  d[0] = bf16tof((u16)(u.x & 0xffff)); d[1] = bf16tof((u16)(u.x >> 16));
  d[2] = bf16tof((u16)(u.y & 0xffff)); d[3] = bf16tof((u16)(u.y >> 16));
  d[4] = bf16tof((u16)(u.z & 0xffff)); d[5] = bf16tof((u16)(u.z >> 16));
  d[6] = bf16tof((u16)(u.w & 0xffff)); d[7] = bf16tof((u16)(u.w >> 16));
}

__device__ __forceinline__ void glds16(const void* g, void* l) {
  __builtin_amdgcn_global_load_lds(
      (const __attribute__((address_space(1))) unsigned int*)g,
      (__attribute__((address_space(3))) unsigned int*)l, 16, 0, 0);
}

// ---------- kernel 1: per-block mean (block node) ----------
__global__ __launch_bounds__(256) void mean_kernel(const float* __restrict__ x,
                                                   float* __restrict__ bn) {
  const int blk = blockIdx.x;
  const int c = threadIdx.x;
  const float* p = x + (size_t)blk * BS_ * C_ + c;
  float s = 0.f;
  #pragma unroll 4
  for (int r = 0; r < BS_; ++r) s += p[(size_t)r * C_];
  bn[(size_t)blk * C_ + c] = s * (1.0f / BS_);
}

// ---------- kernel 2: transpose+convert weights ----------
// wtq[n][k] = bf16(w_qkv[k][n]) (768x256); wtp[n][k] = bf16(w_proj[k][n]) (256x256)
__global__ __launch_bounds__(256) void wt_kernel(const float* __restrict__ wq,
      const float* __restrict__ wp, s16* __restrict__ wtq, s16* __restrict__ wtp) {
  const int i = blockIdx.x * 256 + threadIdx.x;
  if (i < 768 * 256) {
    const int nn = i >> 8, k = i & 255;
    wtq[i] = (s16)ftobf16(wq[k * 768 + nn]);
  } else {
    const int j = i - 768 * 256;
    const int nn = j >> 8, k = j & 255;
    wtp[j] = (s16)ftobf16(wp[k * 256 + nn]);
  }
}

// ---------- MFMA bf16 GEMM: C[M][NS] = A[M][256] @ Bt[NS][256]^T + bias ------
// 128x128 tile, BK=64, 4 waves each 64x64 (4x4 frags of 16x16x32).
// LDS XOR swizzle: phys_byte = row*128 + (logical_colbyte ^ ((row&7)<<4)).
// MAP: A staged from f32 x/bn (row g -> blk=g/129, r=g%129; r==128 -> bn),
//      reg-staged with swizzled ds_write. !MAP: A bf16, global_load_lds with
//      pre-swizzled source. B always global_load_lds pre-swizzled from Bt.
template<bool MAP, bool OBF16, int NS>
__global__ __launch_bounds__(256) void mfma_gemm(const s16* __restrict__ Ab,
      const float* __restrict__ xA, const float* __restrict__ bnA,
      const s16* __restrict__ Bt, const float* __restrict__ bias,
      void* __restrict__ outv) {
  __shared__ __align__(16) s16 Al[128 * 64];   // 16 KB
  __shared__ __align__(16) s16 Bl[128 * 64];   // 16 KB
  const int tid = threadIdx.x;
  const int lane = tid & 63;
  const int wid = tid >> 6;
  const int row0 = blockIdx.x * 128;
  const int col0 = blockIdx.y * 128;

  const float* aptr[4];
  if constexpr (MAP) {
    #pragma unroll
    for (int i = 0; i < 4; ++i) {
      const int r = (tid >> 3) + 32 * i;
      const int g = row0 + r;
      const int blk = g / KL_;
      const int rr = g - blk * KL_;
      aptr[i] = (rr < BS_) ? (xA + ((size_t)blk * BS_ + rr) * C_)
                           : (bnA + (size_t)blk * C_);
    }
  }
  const int ldrow = lane >> 3;          // row within 8-row chunk
  const int lcb   = (lane & 7) * 16;    // linear colbyte within row

  f32x4 acc[4][4];
  #pragma unroll
  for (int i = 0; i < 4; ++i)
    #pragma unroll
    for (int j = 0; j < 4; ++j) acc[i][j] = f32x4{0.f, 0.f, 0.f, 0.f};

  for (int k0 = 0; k0 < C_; k0 += 64) {
    // stage B (each wave: 4 x 1KB chunks)
    #pragma unroll
    for (int j = 0; j < 4; ++j) {
      const int c = wid * 4 + j;
      const int row = c * 8 + ldrow;                  // Bt row (= C col)
      const int scb = lcb ^ ((row & 7) << 4);         // pre-swizzled source
      glds16(Bt + (size_t)(col0 + row) * C_ + k0 + (scb >> 1), &Bl[c * 512]);
    }
    // stage A
    if constexpr (MAP) {
      const int c8 = (tid & 7) * 8;
      #pragma unroll
      for (int i = 0; i < 4; ++i) {
        const int row = (tid >> 3) + 32 * i;
        const float* src = aptr[i] + k0 + c8;
        const float4 f0 = *(const float4*)(src);
        const float4 f1 = *(const float4*)(src + 4);
        bf16x8 p;
        p[0] = (__bf16)f0.x; p[1] = (__bf16)f0.y;
        p[2] = (__bf16)f0.z; p[3] = (__bf16)f0.w;
        p[4] = (__bf16)f1.x; p[5] = (__bf16)f1.y;
        p[6] = (__bf16)f1.z; p[7] = (__bf16)f1.w;
        const int cb = (c8 * 2) ^ ((row & 7) << 4);
        *(bf16x8*)((char*)Al + row * 128 + cb) = p;
      }
    } else {
      #pragma unroll
      for (int j = 0; j < 4; ++j) {
        const int c = wid * 4 + j;
        const int row = c * 8 + ldrow;
        const int scb = lcb ^ ((row & 7) << 4);
        glds16(Ab + (size_t)(row0 + row) * C_ + k0 + (scb >> 1), &Al[c * 512]);
      }
    }
    __syncthreads();

    const int fr = lane & 15;
    const int ar0 = (wid >> 1) * 64;
    const int ac0 = (wid & 1) * 64;
    #pragma unroll
    for (int kk = 0; kk < 64; kk += 32) {
      const int kb = kk * 2 + (lane >> 4) * 16;       // logical colbyte
      bf16x8 af[4], bfr[4];
      #pragma unroll
      for (int mf = 0; mf < 4; ++mf) {
        const int row = ar0 + mf * 16 + fr;
        af[mf] = *(const bf16x8*)((const char*)Al + row * 128
                                  + (kb ^ ((row & 7) << 4)));
      }
      #pragma unroll
      for (int nf = 0; nf < 4; ++nf) {
        const int row = ac0 + nf * 16 + fr;
        bfr[nf] = *(const bf16x8*)((const char*)Bl + row * 128
                                   + (kb ^ ((row & 7) << 4)));
      }
      #pragma unroll
      for (int mf = 0; mf < 4; ++mf)
        #pragma unroll
        for (int nf = 0; nf < 4; ++nf)
          acc[mf][nf] = __builtin_amdgcn_mfma_f32_16x16x32_bf16(
              af[mf], bfr[nf], acc[mf][nf], 0, 0, 0);
    }
    __syncthreads();
  }

  const int orow0 = row0 + (wid >> 1) * 64 + (lane >> 4) * 4;
  const int ocol0 = col0 + (wid & 1) * 64 + (lane & 15);
  #pragma unroll
  for (int nf = 0; nf < 4; ++nf) {
    const int col = ocol0 + nf * 16;
    const float bb = bias[col];
    #pragma unroll
    for (int mf = 0; mf < 4; ++mf) {
      #pragma unroll
      for (int r = 0; r < 4; ++r) {
        const size_t row = (size_t)(orow0 + mf * 16 + r);
        const float v = acc[mf][nf][r] + bb;
        if constexpr (OBF16) ((u16*)outv)[row * NS + col] = ftobf16(v);
        else                 ((float*)outv)[row * NS + col] = v;
      }
    }
  }
}

// ---------- kernel 4: fused block attention (head-parallel) ----------
// One WG per (b, block, head). Thread pair per q-row splits the 129-key range.
__global__ __launch_bounds__(256) void attn_kernel(const u16* __restrict__ qkv,
      const int* __restrict__ mask, const float* __restrict__ ef,
      const float* __restrict__ wg_, const float* __restrict__ bg,
      u16* __restrict__ ao) {
  __shared__ float ks[KL_][33];   // padded: conflict-free staging writes
  __shared__ float vs[KL_][33];
  const int bid = blockIdx.x;
  const int wgi = bid >> 3;       // b*NB_ + n
  const int h = bid & 7;
  const int n = wgi & (NB_ - 1);
  const int tid = threadIdx.x;
  const u16* qkv_blk = qkv + (size_t)wgi * KL_ * 768;

  for (int i = tid; i < KL_ * 4; i += 256) {
    const int r = i >> 2, jq = i & 3;
    const u16* rp = qkv_blk + (size_t)r * 768 + h * 32;
    unpack8(*(const uint4*)(rp + 256 + jq * 8), &ks[r][jq * 8]);
    unpack8(*(const uint4*)(rp + 512 + jq * 8), &vs[r][jq * 8]);
  }
  __syncthreads();

  const int qrow = tid >> 1;
  const int kh = tid & 1;
  const int kbeg = kh ? 65 : 0;
  const int kend = kh ? KL_ : 65;
  const int*   mrow = mask + ((size_t)n * BS_ + qrow) * KL_;
  const float* erow = ef + (((size_t)n * BS_ + qrow) * KL_) * 4;

  float qf[32];
  const u16* qp = qkv_blk + (size_t)qrow * 768 + h * 32;
  #pragma unroll
  for (int jj = 0; jj < 4; ++jj)
    unpack8(*(const uint4*)(qp + jj * 8), &qf[jj * 8]);

  const float wgc0 = wg_[h], wgc1 = wg_[8 + h], wgc2 = wg_[16 + h],
              wgc3 = wg_[24 + h], bgh = bg[h];

  float ssum = 0.f;
  float num[32], gac[32];
  #pragma unroll
  for (int j = 0; j < 32; ++j) { num[j] = 0.f; gac[j] = 0.f; }

  for (int k = kbeg; k < kend; ++k) {
    float d0 = 0.f, d1 = 0.f, d2 = 0.f, d3 = 0.f;
    #pragma unroll
    for (int j = 0; j < 8; ++j) {
      d0 += qf[4*j+0] * ks[k][4*j+0];
      d1 += qf[4*j+1] * ks[k][4*j+1];
      d2 += qf[4*j+2] * ks[k][4*j+2];
      d3 += qf[4*j+3] * ks[k][4*j+3];
    }
    const float logit = (d0 + d1) + (d2 + d3);
    const int m = mrow[k];
    float4 e = *(const float4*)(erow + (size_t)k * 4);
    const bool sp = (k == BS_) | (k == qrow);
    if (sp) { e.x = 0.f; e.y = 0.f; e.z = 0.f; e.w = 1.f; }
    const float sadd = m ? e.w : -1e30f;
    const float gt = m ? (e.x * wgc0 + e.y * wgc1 + e.z * wgc2
                          + e.w * wgc3 + bgh) : 0.f;
    const float w = __expf(logit * SCALE_ + sadd);
    ssum += w;
    #pragma unroll
    for (int j = 0; j < 32; ++j) {
      const float vv = vs[k][j];
      num[j] += w * vv;
      gac[j] += gt * vv;
    }
  }
  ssum += __shfl_xor(ssum, 1);
  #pragma unroll
  for (int j = 0; j < 32; ++j) {
    num[j] += __shfl_xor(num[j], 1);
    gac[j] += __shfl_xor(gac[j], 1);
  }
  const float inv = 1.0f / ssum;
  const int base = kh * 16;
  u16* aop = ao + (((size_t)wgi * BS_ + qrow) * C_ + h * 32 + base);
  u32 p[8];
  #pragma unroll
  for (int j = 0; j < 8; ++j) {
    const float o0 = num[base + 2*j]     * inv + gac[base + 2*j];
    const float o1 = num[base + 2*j + 1] * inv + gac[base + 2*j + 1];
    p[j] = (u32)ftobf16(o0) | ((u32)ftobf16(o1) << 16);
  }
  uint4 s0; s0.x = p[0]; s0.y = p[1]; s0.z = p[2]; s0.w = p[3];
  uint4 s1; s1.x = p[4]; s1.y = p[5]; s1.z = p[6]; s1.w = p[7];
  *(uint4*)(aop)     = s0;
  *(uint4*)(aop + 8) = s1;
}

extern "C" void kernel_launch(void* const* d_in, const int* in_sizes, int n_in,
                              void* d_out, int out_size, void* d_ws, size_t ws_size,
                              hipStream_t stream) {
  (void)in_sizes; (void)n_in; (void)out_size; (void)ws_size;
  const float* x      = (const float*)d_in[0];
  const int*   mask   = (const int*)  d_in[1];
  const float* ef     = (const float*)d_in[2];
  const float* w_qkv  = (const float*)d_in[3];
  const float* b_qkv  = (const float*)d_in[4];
  const float* w_proj = (const float*)d_in[5];
  const float* b_proj = (const float*)d_in[6];
  const float* w_gate = (const float*)d_in[7];
  const float* b_gate = (const float*)d_in[8];
  float* out = (float*)d_out;
  char* ws = (char*)d_ws;

  // workspace layout (bytes), total 136,052,736
  float* bn  = (float*)(ws);                 //       524,288
  u16*   qkv = (u16*)(ws + 524288);          //   101,449,728
  u16*   ao  = (u16*)(ws + 101974016);       //    33,554,432
  s16*   wtq = (s16*)(ws + 135528448);       //       393,216
  s16*   wtp = (s16*)(ws + 135921664);       //       131,072

  mean_kernel<<<B_ * NB_, 256, 0, stream>>>(x, bn);
  wt_kernel<<<(768 * 256 + 256 * 256) / 256, 256, 0, stream>>>(
      w_qkv, w_proj, wtq, wtp);
  mfma_gemm<true, true, 768>
      <<<dim3((B_ * NB_ * KL_) / 128, 6), 256, 0, stream>>>(
      nullptr, x, bn, wtq, b_qkv, qkv);
  attn_kernel<<<B_ * NB_ * H_, 256, 0, stream>>>(
      (const u16*)qkv, mask, ef, w_gate, b_gate, ao);
  mfma_gemm<false, false, 256>
      <<<dim3((B_ * NB_ * BS_) / 128, 2), 256, 0, stream>>>(
      (const s16*)ao, nullptr, nullptr, wtp, b_proj, out);
}

// Round 4
// 521.302 us; speedup vs baseline: 4.8657x; 4.8657x over previous
//
#include <hip/hip_runtime.h>

#define B_   4
#define NB_  128
#define BS_  128
#define C_   256
#define H_   8
#define KL_  129   // BS_+1
#define SC2_   0.25503486f   // (1/sqrt(32)) * log2(e)
#define LOG2E_ 1.4426950f

typedef unsigned short u16;
typedef unsigned int   u32;
typedef short          s16;
typedef __attribute__((ext_vector_type(8))) __bf16 bf16x8;
typedef __attribute__((ext_vector_type(4))) float  f32x4;

__device__ __forceinline__ float bf16tof(u16 u) {
  union { u32 i; float f; } v; v.i = ((u32)u) << 16; return v.f;
}
__device__ __forceinline__ u16 ftobf16(float f) {
  union { float f; u32 i; } v; v.f = f;
  u32 b = v.i + 0x7FFFu + ((v.i >> 16) & 1u);
  return (u16)(b >> 16);
}

__device__ __forceinline__ void glds16(const void* g, void* l) {
  __builtin_amdgcn_global_load_lds(
      (const __attribute__((address_space(1))) unsigned int*)g,
      (__attribute__((address_space(3))) unsigned int*)l, 16, 0, 0);
}

// ---------- kernel 1: per-block mean (block node) ----------
__global__ __launch_bounds__(256) void mean_kernel(const float* __restrict__ x,
                                                   float* __restrict__ bn) {
  const int blk = blockIdx.x;
  const int c = threadIdx.x;
  const float* p = x + (size_t)blk * BS_ * C_ + c;
  float s = 0.f;
  #pragma unroll 4
  for (int r = 0; r < BS_; ++r) s += p[(size_t)r * C_];
  bn[(size_t)blk * C_ + c] = s * (1.0f / BS_);
}

// ---------- kernel 2: transpose+convert weights ----------
__global__ __launch_bounds__(256) void wt_kernel(const float* __restrict__ wq,
      const float* __restrict__ wp, s16* __restrict__ wtq, s16* __restrict__ wtp) {
  const int i = blockIdx.x * 256 + threadIdx.x;
  if (i < 768 * 256) {
    const int nn = i >> 8, k = i & 255;
    wtq[i] = (s16)ftobf16(wq[k * 768 + nn]);
  } else {
    const int j = i - 768 * 256;
    const int nn = j >> 8, k = j & 255;
    wtp[j] = (s16)ftobf16(wp[k * 256 + nn]);
  }
}

// ---------- MFMA bf16 GEMM (unchanged from round 3, verified) ----------
template<bool MAP, bool OBF16, int NS>
__global__ __launch_bounds__(256) void mfma_gemm(const s16* __restrict__ Ab,
      const float* __restrict__ xA, const float* __restrict__ bnA,
      const s16* __restrict__ Bt, const float* __restrict__ bias,
      void* __restrict__ outv) {
  __shared__ __align__(16) s16 Al[128 * 64];
  __shared__ __align__(16) s16 Bl[128 * 64];
  const int tid = threadIdx.x;
  const int lane = tid & 63;
  const int wid = tid >> 6;
  const int row0 = blockIdx.x * 128;
  const int col0 = blockIdx.y * 128;

  const float* aptr[4];
  if constexpr (MAP) {
    #pragma unroll
    for (int i = 0; i < 4; ++i) {
      const int r = (tid >> 3) + 32 * i;
      const int g = row0 + r;
      const int blk = g / KL_;
      const int rr = g - blk * KL_;
      aptr[i] = (rr < BS_) ? (xA + ((size_t)blk * BS_ + rr) * C_)
                           : (bnA + (size_t)blk * C_);
    }
  }
  const int ldrow = lane >> 3;
  const int lcb   = (lane & 7) * 16;

  f32x4 acc[4][4];
  #pragma unroll
  for (int i = 0; i < 4; ++i)
    #pragma unroll
    for (int j = 0; j < 4; ++j) acc[i][j] = f32x4{0.f, 0.f, 0.f, 0.f};

  for (int k0 = 0; k0 < C_; k0 += 64) {
    #pragma unroll
    for (int j = 0; j < 4; ++j) {
      const int c = wid * 4 + j;
      const int row = c * 8 + ldrow;
      const int scb = lcb ^ ((row & 7) << 4);
      glds16(Bt + (size_t)(col0 + row) * C_ + k0 + (scb >> 1), &Bl[c * 512]);
    }
    if constexpr (MAP) {
      const int c8 = (tid & 7) * 8;
      #pragma unroll
      for (int i = 0; i < 4; ++i) {
        const int row = (tid >> 3) + 32 * i;
        const float* src = aptr[i] + k0 + c8;
        const float4 f0 = *(const float4*)(src);
        const float4 f1 = *(const float4*)(src + 4);
        bf16x8 p;
        p[0] = (__bf16)f0.x; p[1] = (__bf16)f0.y;
        p[2] = (__bf16)f0.z; p[3] = (__bf16)f0.w;
        p[4] = (__bf16)f1.x; p[5] = (__bf16)f1.y;
        p[6] = (__bf16)f1.z; p[7] = (__bf16)f1.w;
        const int cb = (c8 * 2) ^ ((row & 7) << 4);
        *(bf16x8*)((char*)Al + row * 128 + cb) = p;
      }
    } else {
      #pragma unroll
      for (int j = 0; j < 4; ++j) {
        const int c = wid * 4 + j;
        const int row = c * 8 + ldrow;
        const int scb = lcb ^ ((row & 7) << 4);
        glds16(Ab + (size_t)(row0 + row) * C_ + k0 + (scb >> 1), &Al[c * 512]);
      }
    }
    __syncthreads();

    const int fr = lane & 15;
    const int ar0 = (wid >> 1) * 64;
    const int ac0 = (wid & 1) * 64;
    #pragma unroll
    for (int kk = 0; kk < 64; kk += 32) {
      const int kb = kk * 2 + (lane >> 4) * 16;
      bf16x8 af[4], bfr[4];
      #pragma unroll
      for (int mf = 0; mf < 4; ++mf) {
        const int row = ar0 + mf * 16 + fr;
        af[mf] = *(const bf16x8*)((const char*)Al + row * 128
                                  + (kb ^ ((row & 7) << 4)));
      }
      #pragma unroll
      for (int nf = 0; nf < 4; ++nf) {
        const int row = ac0 + nf * 16 + fr;
        bfr[nf] = *(const bf16x8*)((const char*)Bl + row * 128
                                   + (kb ^ ((row & 7) << 4)));
      }
      #pragma unroll
      for (int mf = 0; mf < 4; ++mf)
        #pragma unroll
        for (int nf = 0; nf < 4; ++nf)
          acc[mf][nf] = __builtin_amdgcn_mfma_f32_16x16x32_bf16(
              af[mf], bfr[nf], acc[mf][nf], 0, 0, 0);
    }
    __syncthreads();
  }

  const int orow0 = row0 + (wid >> 1) * 64 + (lane >> 4) * 4;
  const int ocol0 = col0 + (wid & 1) * 64 + (lane & 15);
  #pragma unroll
  for (int nf = 0; nf < 4; ++nf) {
    const int col = ocol0 + nf * 16;
    const float bb = bias[col];
    #pragma unroll
    for (int mf = 0; mf < 4; ++mf) {
      #pragma unroll
      for (int r = 0; r < 4; ++r) {
        const size_t row = (size_t)(orow0 + mf * 16 + r);
        const float v = acc[mf][nf][r] + bb;
        if constexpr (OBF16) ((u16*)outv)[row * NS + col] = ftobf16(v);
        else                 ((float*)outv)[row * NS + col] = v;
      }
    }
  }
}

// ---------- kernel 4: MFMA fused block attention ----------
// Grid: (b*NB+n)*2 + hg; 4 waves, wave wid -> head hg*4+wid; no barriers.
// Swapped QK^T: S^T = mfma(A=K-frag, B=Q-frag): lane holds S^T[key=16f+4g+r][q=16mt+ql].
// coeff = softmax(w)*inv + gate, bf16 -> P LDS tile -> PV A-frags.
// V transposed into LDS once per wave; PV B-frags via ds_read_b128.
__global__ __launch_bounds__(256, 2) void attn_kernel(const u16* __restrict__ qkv,
      const int* __restrict__ mask, const float* __restrict__ ef,
      const float* __restrict__ wg_, const float* __restrict__ bg,
      u16* __restrict__ ao) {
  __shared__ __align__(16) char lds[4 * 14080];   // per wave: V^T[32][136] + P[16][168]
  const int bid = blockIdx.x;
  const int wgi = bid >> 1;
  const int hg  = bid & 1;
  const int n = wgi & (NB_ - 1);
  const int tid = threadIdx.x;
  const int wid = tid >> 6, lane = tid & 63;
  const int h = hg * 4 + wid;
  const int g = lane >> 4, ql = lane & 15;
  char* wbase = lds + wid * 14080;
  u16* vt = (u16*)wbase;               // [32][136] bf16
  char* pb = wbase + 8704;             // [16][168] bf16

  const u16* qkv_blk = qkv + (size_t)wgi * KL_ * 768;

  // stage V^T (raw bf16 bits, transposed)
  #pragma unroll
  for (int it = 0; it < 9; ++it) {
    const int idx = it * 64 + lane;
    if (idx < 516) {
      const int r = idx >> 2, dc = idx & 3;
      const uint4 u = *(const uint4*)(qkv_blk + (size_t)r * 768 + 512 + h * 32 + dc * 8);
      u16* col = vt + (dc * 8) * 136 + r;
      col[0 * 136] = (u16)(u.x & 0xffff); col[1 * 136] = (u16)(u.x >> 16);
      col[2 * 136] = (u16)(u.y & 0xffff); col[3 * 136] = (u16)(u.y >> 16);
      col[4 * 136] = (u16)(u.z & 0xffff); col[5 * 136] = (u16)(u.z >> 16);
      col[6 * 136] = (u16)(u.w & 0xffff); col[7 * 136] = (u16)(u.w >> 16);
    }
  }
  // zero P keys 144..159 (PV chunk 4 reads them; coeff stores cover only <=143)
  *(uint2*)(pb + ql * 336 + 288 + 8 * g) = uint2{0u, 0u};

  // K fragments (A-operand): row=ql -> key 16f+ql, k-dim=g*8+j -> channel
  bf16x8 kf[9];
  #pragma unroll
  for (int f = 0; f < 9; ++f)
    kf[f] = *(const bf16x8*)(qkv_blk + (size_t)(16 * f + ql) * 768 + 256 + h * 32 + g * 8);

  // V fragments (B-operand) from V^T LDS: col=ql -> d, k-dim -> key
  bf16x8 vf[5][2];
  #pragma unroll
  for (int c = 0; c < 5; ++c)
    #pragma unroll
    for (int nf = 0; nf < 2; ++nf)
      vf[c][nf] = *(const bf16x8*)(vt + (nf * 16 + ql) * 136 + 32 * c + 8 * g);

  const float wgc0 = wg_[h], wgc1 = wg_[8 + h], wgc2 = wg_[16 + h], wgc3 = wg_[24 + h];
  const float bgh = bg[h];
  const float gk128 = wgc3 + bgh;   // gate at global-node col (mask==1 guaranteed)

  #pragma unroll 1
  for (int mt = 0; mt < 8; ++mt) {
    const int qrow = mt * 16 + ql;
    const bf16x8 qf = *(const bf16x8*)(qkv_blk + (size_t)qrow * 768 + h * 32 + g * 8);
    f32x4 st[9];
    #pragma unroll
    for (int f = 0; f < 9; ++f)
      st[f] = __builtin_amdgcn_mfma_f32_16x16x32_bf16(kf[f], qf,
                                                      f32x4{0.f, 0.f, 0.f, 0.f}, 0, 0, 0);
    const int*   mq = mask + ((size_t)n * BS_ + qrow) * KL_;
    const float* eq = ef + ((size_t)n * BS_ + qrow) * KL_ * 4;
    f32x4 ga[9];
    float psum = 0.f;
    #pragma unroll
    for (int f = 0; f < 8; ++f) {
      #pragma unroll
      for (int r = 0; r < 4; ++r) {
        const int key = 16 * f + 4 * g + r;       // < 128
        const int m = mq[key];
        const float4 e = *(const float4*)(eq + (size_t)key * 4);
        const bool dg = (key == qrow);
        const float e0 = dg ? 0.f : e.x, e1 = dg ? 0.f : e.y,
                    e2 = dg ? 0.f : e.z, e3 = dg ? 1.f : e.w;
        const float sadd = m ? e3 * LOG2E_ : -1e30f;
        const float gt = m ? (e0 * wgc0 + e1 * wgc1 + e2 * wgc2 + e3 * wgc3 + bgh) : 0.f;
        const float w = __builtin_amdgcn_exp2f(fmaf(st[f][r], SC2_, sadd));
        psum += w;
        st[f][r] = w;
        ga[f][r] = gt;
      }
    }
    #pragma unroll
    for (int r = 0; r < 4; ++r) {                 // f==8: keys 128..143
      const bool is128 = (g == 0) && (r == 0);
      const float sadd = is128 ? LOG2E_ : -1e30f;
      const float w = __builtin_amdgcn_exp2f(fmaf(st[8][r], SC2_, sadd));
      psum += w;
      st[8][r] = w;
      ga[8][r] = is128 ? gk128 : 0.f;
    }
    psum += __shfl_xor(psum, 16);
    psum += __shfl_xor(psum, 32);
    const float inv = __builtin_amdgcn_rcpf(psum);
    #pragma unroll
    for (int f = 0; f < 9; ++f) {
      const float c0 = fmaf(st[f][0], inv, ga[f][0]);
      const float c1 = fmaf(st[f][1], inv, ga[f][1]);
      const float c2 = fmaf(st[f][2], inv, ga[f][2]);
      const float c3 = fmaf(st[f][3], inv, ga[f][3]);
      uint2 pw;
      pw.x = (u32)ftobf16(c0) | ((u32)ftobf16(c1) << 16);
      pw.y = (u32)ftobf16(c2) | ((u32)ftobf16(c3) << 16);
      *(uint2*)(pb + ql * 336 + (16 * f + 4 * g) * 2) = pw;
    }
    f32x4 o0{0.f, 0.f, 0.f, 0.f}, o1{0.f, 0.f, 0.f, 0.f};
    #pragma unroll
    for (int c = 0; c < 5; ++c) {
      const bf16x8 pa = *(const bf16x8*)(pb + ql * 336 + (32 * c + 8 * g) * 2);
      o0 = __builtin_amdgcn_mfma_f32_16x16x32_bf16(pa, vf[c][0], o0, 0, 0, 0);
      o1 = __builtin_amdgcn_mfma_f32_16x16x32_bf16(pa, vf[c][1], o1, 0, 0, 0);
    }
    u16* aop = ao + ((size_t)wgi * BS_ + mt * 16 + g * 4) * C_ + h * 32 + ql;
    #pragma unroll
    for (int r = 0; r < 4; ++r) {
      aop[(size_t)r * C_]      = ftobf16(o0[r]);
      aop[(size_t)r * C_ + 16] = ftobf16(o1[r]);
    }
  }
}

extern "C" void kernel_launch(void* const* d_in, const int* in_sizes, int n_in,
                              void* d_out, int out_size, void* d_ws, size_t ws_size,
                              hipStream_t stream) {
  (void)in_sizes; (void)n_in; (void)out_size; (void)ws_size;
  const float* x      = (const float*)d_in[0];
  const int*   mask   = (const int*)  d_in[1];
  const float* ef     = (const float*)d_in[2];
  const float* w_qkv  = (const float*)d_in[3];
  const float* b_qkv  = (const float*)d_in[4];
  const float* w_proj = (const float*)d_in[5];
  const float* b_proj = (const float*)d_in[6];
  const float* w_gate = (const float*)d_in[7];
  const float* b_gate = (const float*)d_in[8];
  float* out = (float*)d_out;
  char* ws = (char*)d_ws;

  // workspace layout (bytes), total 136,052,736 (<= proven budget)
  float* bn  = (float*)(ws);                 //       524,288
  u16*   qkv = (u16*)(ws + 524288);          //   101,449,728
  u16*   ao  = (u16*)(ws + 101974016);       //    33,554,432
  s16*   wtq = (s16*)(ws + 135528448);       //       393,216
  s16*   wtp = (s16*)(ws + 135921664);       //       131,072

  mean_kernel<<<B_ * NB_, 256, 0, stream>>>(x, bn);
  wt_kernel<<<(768 * 256 + 256 * 256) / 256, 256, 0, stream>>>(
      w_qkv, w_proj, wtq, wtp);
  mfma_gemm<true, true, 768>
      <<<dim3((B_ * NB_ * KL_) / 128, 6), 256, 0, stream>>>(
      nullptr, x, bn, wtq, b_qkv, qkv);
  attn_kernel<<<B_ * NB_ * 2, 256, 0, stream>>>(
      (const u16*)qkv, mask, ef, w_gate, b_gate, ao);
  mfma_gemm<false, false, 256>
      <<<dim3((B_ * NB_ * BS_) / 128, 2), 256, 0, stream>>>(
      (const s16*)ao, nullptr, nullptr, wtp, b_proj, out);
}

// Round 7
// 238.752 us; speedup vs baseline: 10.6239x; 2.1834x over previous
//
#include <hip/hip_runtime.h>

#define B_   4
#define NB_  128
#define BS_  128
#define C_   256
#define H_   8
#define KL_  129   // BS_+1
#define SC2_   0.25503486f           // (1/sqrt(32)) * log2(e)
#define LOG2E_ 1.4426950408889634f
#define LN2_   0.6931471805599453f
#define RSTR_  99072                 // KL_*768: u16 stride of one block in qkv
#define WREG_  15616                 // per-wave LDS: V^T[32][160] + P[16][336B]

typedef unsigned short u16;
typedef unsigned int   u32;
typedef short          s16;
typedef __attribute__((ext_vector_type(8))) __bf16 bf16x8;
typedef __attribute__((ext_vector_type(4))) float  f32x4;

__device__ __forceinline__ u16 ftobf16(float f) {
  union { float f; u32 i; } v; v.f = f;
  u32 b = v.i + 0x7FFFu + ((v.i >> 16) & 1u);
  return (u16)(b >> 16);
}
__device__ __forceinline__ float asf(u32 u) {
  union { u32 i; float f; } v; v.i = u; return v.f;
}

__device__ __forceinline__ void glds16(const void* g, void* l) {
  __builtin_amdgcn_global_load_lds(
      (const __attribute__((address_space(1))) unsigned int*)g,
      (__attribute__((address_space(3))) unsigned int*)l, 16, 0, 0);
}

// ---------- kernel 1: per-block mean (block node) ----------
__global__ __launch_bounds__(256) void mean_kernel(const float* __restrict__ x,
                                                   float* __restrict__ bn) {
  const int blk = blockIdx.x;
  const int c = threadIdx.x;
  const float* p = x + (size_t)blk * BS_ * C_ + c;
  float s = 0.f;
  #pragma unroll 4
  for (int r = 0; r < BS_; ++r) s += p[(size_t)r * C_];
  bn[(size_t)blk * C_ + c] = s * (1.0f / BS_);
}

// ---------- kernel 2: transpose+convert weights ----------
__global__ __launch_bounds__(256) void wt_kernel(const float* __restrict__ wq,
      const float* __restrict__ wp, s16* __restrict__ wtq, s16* __restrict__ wtp) {
  const int i = blockIdx.x * 256 + threadIdx.x;
  if (i < 768 * 256) {
    const int nn = i >> 8, k = i & 255;
    wtq[i] = (s16)ftobf16(wq[k * 768 + nn]);
  } else {
    const int j = i - 768 * 256;
    const int nn = j >> 8, k = j & 255;
    wtp[j] = (s16)ftobf16(wp[k * 256 + nn]);
  }
}

// ---------- kernel 3: edge-bias precompute ----------
// e4t[n][q][key<128] = 4 bf16 {e0, e1, e2, e3*log2e}; diag -> (0,0,0,log2e);
// masked -> (0,0,0,-1e30). Key 128 handled in attn (always unmasked).
__global__ __launch_bounds__(256) void pre_kernel(const int* __restrict__ mask,
      const float* __restrict__ ef, u16* __restrict__ e4t) {
  const int t = blockIdx.x * 256 + threadIdx.x;   // (n*128+q)*32 + kq
  const int kq = t & 31;
  const int row = t >> 5;                          // n*128+q
  const int q = row & 127;
  const int key0 = kq * 4;
  const int* mrow = mask + (size_t)row * KL_;
  const float* erow = ef + (size_t)row * KL_ * 4;
  u32 o[8];
  #pragma unroll
  for (int r = 0; r < 4; ++r) {
    const int key = key0 + r;
    const int m = mrow[key];
    float4 e = *(const float4*)(erow + (size_t)key * 4);
    if (key == q) { e.x = 0.f; e.y = 0.f; e.z = 0.f; e.w = 1.f; }
    float e3L = e.w * LOG2E_;
    if (!m) { e.x = 0.f; e.y = 0.f; e.z = 0.f; e3L = -1e30f; }
    o[2*r]   = (u32)ftobf16(e.x) | ((u32)ftobf16(e.y) << 16);
    o[2*r+1] = (u32)ftobf16(e.z) | ((u32)ftobf16(e3L) << 16);
  }
  uint4* dst = (uint4*)(e4t + (size_t)row * 512 + key0 * 4);
  dst[0] = uint4{o[0], o[1], o[2], o[3]};
  dst[1] = uint4{o[4], o[5], o[6], o[7]};
}

// ---------- MFMA bf16 GEMM ----------
// MAP: A from f32 x/bn (row g -> blk=g/129, r=g%129; r==128 -> bn).
// STRIDED: A bf16 from qkv K-plane: row -> qkv + blockIdx.x*RSTR_ + row*768 + 256.
template<bool MAP, bool STRIDED, bool OBF16, int NS>
__global__ __launch_bounds__(256) void mfma_gemm(const s16* __restrict__ Ab,
      const float* __restrict__ xA, const float* __restrict__ bnA,
      const s16* __restrict__ Bt, const float* __restrict__ bias,
      void* __restrict__ outv) {
  __shared__ __align__(16) s16 Al[128 * 64];
  __shared__ __align__(16) s16 Bl[128 * 64];
  const int tid = threadIdx.x;
  const int lane = tid & 63;
  const int wid = tid >> 6;
  const int row0 = blockIdx.x * 128;
  const int col0 = blockIdx.y * 128;

  const float* aptr[4];
  if constexpr (MAP) {
    #pragma unroll
    for (int i = 0; i < 4; ++i) {
      const int r = (tid >> 3) + 32 * i;
      const int g = row0 + r;
      const int blk = g / KL_;
      const int rr = g - blk * KL_;
      aptr[i] = (rr < BS_) ? (xA + ((size_t)blk * BS_ + rr) * C_)
                           : (bnA + (size_t)blk * C_);
    }
  }
  const int ldrow = lane >> 3;
  const int lcb   = (lane & 7) * 16;
  const size_t abase = (size_t)blockIdx.x * RSTR_ + 256;  // STRIDED only

  f32x4 acc[4][4];
  #pragma unroll
  for (int i = 0; i < 4; ++i)
    #pragma unroll
    for (int j = 0; j < 4; ++j) acc[i][j] = f32x4{0.f, 0.f, 0.f, 0.f};

  for (int k0 = 0; k0 < C_; k0 += 64) {
    #pragma unroll
    for (int j = 0; j < 4; ++j) {
      const int c = wid * 4 + j;
      const int row = c * 8 + ldrow;
      const int scb = lcb ^ ((row & 7) << 4);
      glds16(Bt + (size_t)(col0 + row) * C_ + k0 + (scb >> 1), &Bl[c * 512]);
    }
    if constexpr (MAP) {
      const int c8 = (tid & 7) * 8;
      #pragma unroll
      for (int i = 0; i < 4; ++i) {
        const int row = (tid >> 3) + 32 * i;
        const float* src = aptr[i] + k0 + c8;
        const float4 f0 = *(const float4*)(src);
        const float4 f1 = *(const float4*)(src + 4);
        bf16x8 p;
        p[0] = (__bf16)f0.x; p[1] = (__bf16)f0.y;
        p[2] = (__bf16)f0.z; p[3] = (__bf16)f0.w;
        p[4] = (__bf16)f1.x; p[5] = (__bf16)f1.y;
        p[6] = (__bf16)f1.z; p[7] = (__bf16)f1.w;
        const int cb = (c8 * 2) ^ ((row & 7) << 4);
        *(bf16x8*)((char*)Al + row * 128 + cb) = p;
      }
    } else {
      #pragma unroll
      for (int j = 0; j < 4; ++j) {
        const int c = wid * 4 + j;
        const int row = c * 8 + ldrow;
        const int scb = lcb ^ ((row & 7) << 4);
        if constexpr (STRIDED)
          glds16(Ab + abase + (size_t)row * 768 + k0 + (scb >> 1), &Al[c * 512]);
        else
          glds16(Ab + (size_t)(row0 + row) * C_ + k0 + (scb >> 1), &Al[c * 512]);
      }
    }
    __syncthreads();

    const int fr = lane & 15;
    const int ar0 = (wid >> 1) * 64;
    const int ac0 = (wid & 1) * 64;
    #pragma unroll
    for (int kk = 0; kk < 64; kk += 32) {
      const int kb = kk * 2 + (lane >> 4) * 16;
      bf16x8 af[4], bfr[4];
      #pragma unroll
      for (int mf = 0; mf < 4; ++mf) {
        const int row = ar0 + mf * 16 + fr;
        af[mf] = *(const bf16x8*)((const char*)Al + row * 128
                                  + (kb ^ ((row & 7) << 4)));
      }
      #pragma unroll
      for (int nf = 0; nf < 4; ++nf) {
        const int row = ac0 + nf * 16 + fr;
        bfr[nf] = *(const bf16x8*)((const char*)Bl + row * 128
                                   + (kb ^ ((row & 7) << 4)));
      }
      #pragma unroll
      for (int mf = 0; mf < 4; ++mf)
        #pragma unroll
        for (int nf = 0; nf < 4; ++nf)
          acc[mf][nf] = __builtin_amdgcn_mfma_f32_16x16x32_bf16(
              af[mf], bfr[nf], acc[mf][nf], 0, 0, 0);
    }
    __syncthreads();
  }

  const int orow0 = row0 + (wid >> 1) * 64 + (lane >> 4) * 4;
  const int ocol0 = col0 + (wid & 1) * 64 + (lane & 15);
  #pragma unroll
  for (int nf = 0; nf < 4; ++nf) {
    const int col = ocol0 + nf * 16;
    const float bb = bias[col];
    #pragma unroll
    for (int mf = 0; mf < 4; ++mf) {
      #pragma unroll
      for (int r = 0; r < 4; ++r) {
        const size_t row = (size_t)(orow0 + mf * 16 + r);
        const float v = acc[mf][nf][r] + bb;
        if constexpr (OBF16) ((u16*)outv)[row * NS + col] = ftobf16(v);
        else                 ((float*)outv)[row * NS + col] = v;
      }
    }
  }
}

// ---------- kernel 5: MFMA fused block attention (round-4 structure) ----------
// Grid (b*NB+n)*2+hg; wave wid -> head hg*4+wid; no cross-wave LDS sharing.
// V^T rows widened to 160 u16 with cols 128..159 zeroed (fixes the chunk-4
// overread). All LDS bytes read are written first.
template<bool INPLACE>
__global__ __launch_bounds__(256, 2) void attn_kernel(u16* __restrict__ qkv,
      const u16* __restrict__ e4t, const float* __restrict__ wg_,
      const float* __restrict__ bg, u16* __restrict__ ao) {
  __shared__ __align__(16) char lds[4 * WREG_];   // 62464 B
  const int bid = blockIdx.x;
  const int wgi = bid >> 1;
  const int hg  = bid & 1;
  const int n = wgi & (NB_ - 1);
  const int tid = threadIdx.x;
  const int wid = tid >> 6, lane = tid & 63;
  const int h = hg * 4 + wid;
  const int g = lane >> 4, ql = lane & 15;
  char* wbase = lds + wid * WREG_;
  u16* vt = (u16*)wbase;               // [32][160] bf16 V^T
  char* pb = wbase + 10240;            // 16 rows x 336 B P tile

  u16* qkv_blk = qkv + (size_t)wgi * RSTR_;
  const u16* ebase = e4t + (size_t)n * (128 * 512);

  // zero V^T cols 128..159 (staging rewrites col 128 with real key-128 data)
  if (lane < 32) {
    uint4* zp = (uint4*)(vt + lane * 160 + 128);
    zp[0] = uint4{0u,0u,0u,0u}; zp[1] = uint4{0u,0u,0u,0u};
    zp[2] = uint4{0u,0u,0u,0u}; zp[3] = uint4{0u,0u,0u,0u};
  }
  // stage V^T (raw bf16 bits, transposed)
  #pragma unroll
  for (int it = 0; it < 9; ++it) {
    const int idx = it * 64 + lane;
    if (idx < 516) {
      const int r = idx >> 2, dc = idx & 3;
      const uint4 u = *(const uint4*)(qkv_blk + (size_t)r * 768 + 512 + h * 32 + dc * 8);
      u16* col = vt + (dc * 8) * 160 + r;
      col[0 * 160] = (u16)(u.x & 0xffff); col[1 * 160] = (u16)(u.x >> 16);
      col[2 * 160] = (u16)(u.y & 0xffff); col[3 * 160] = (u16)(u.y >> 16);
      col[4 * 160] = (u16)(u.z & 0xffff); col[5 * 160] = (u16)(u.z >> 16);
      col[6 * 160] = (u16)(u.w & 0xffff); col[7 * 160] = (u16)(u.w >> 16);
    }
  }

  // K frags (A-operand); f=8 rows clamped in-bounds (dups masked to w=0)
  bf16x8 kf[9];
  #pragma unroll
  for (int f = 0; f < 9; ++f) {
    int kr = 16 * f + ql; if (kr > 128) kr = 128;
    kf[f] = *(const bf16x8*)(qkv_blk + (size_t)kr * 768 + 256 + h * 32 + g * 8);
  }
  // V frags (B-operand) from V^T; chunk 4 tail reads the zeroed cols
  bf16x8 vf[5][2];
  #pragma unroll
  for (int c = 0; c < 5; ++c)
    #pragma unroll
    for (int nf = 0; nf < 2; ++nf)
      vf[c][nf] = *(const bf16x8*)(vt + (nf * 16 + ql) * 160 + 32 * c + 8 * g);

  // zero P tail keys 144..159
  *(uint2*)(pb + ql * 336 + 288 + 8 * g) = uint2{0u, 0u};

  const float wgc0 = wg_[h], wgc1 = wg_[8 + h], wgc2 = wg_[16 + h];
  const float wgc3s = wg_[24 + h] * LN2_;   // pairs with e3*log2e
  const float bgh = bg[h];
  const float gk128 = wg_[24 + h] + bgh;

  #pragma unroll 1
  for (int mt = 0; mt < 8; ++mt) {
    const int qrow = mt * 16 + ql;
    const bf16x8 qf = *(const bf16x8*)(qkv_blk + (size_t)qrow * 768 + h * 32 + g * 8);
    const uint4* eql = (const uint4*)(ebase + (size_t)qrow * 512) + 2 * g;

    f32x4 st[9], ga[9];
    #pragma unroll
    for (int f = 0; f < 9; ++f)
      st[f] = __builtin_amdgcn_mfma_f32_16x16x32_bf16(
          kf[f], qf, f32x4{0.f, 0.f, 0.f, 0.f}, 0, 0, 0);

    float psum = 0.f;
    #pragma unroll
    for (int f = 0; f < 8; ++f) {
      const uint4 ea = eql[8 * f];
      const uint4 eb = eql[8 * f + 1];
      const u32 wa[4] = {ea.x, ea.z, eb.x, eb.z};
      const u32 wb[4] = {ea.y, ea.w, eb.y, eb.w};
      #pragma unroll
      for (int r = 0; r < 4; ++r) {
        const float e0 = asf(wa[r] << 16), e1 = asf(wa[r] & 0xffff0000u);
        const float e2 = asf(wb[r] << 16), e3L = asf(wb[r] & 0xffff0000u);
        const float gg = fmaf(e0, wgc0, fmaf(e1, wgc1,
                          fmaf(e2, wgc2, fmaf(e3L, wgc3s, bgh))));
        ga[f][r] = (e3L > -1e29f) ? gg : 0.f;
        const float w = __builtin_amdgcn_exp2f(fmaf(st[f][r], SC2_, e3L));
        st[f][r] = w;
        psum += w;
      }
    }
    {   // f == 8: only key 128 real (always unmasked)
      const float s0 = (g == 0) ? LOG2E_ : -1e30f;
      const float w0 = __builtin_amdgcn_exp2f(fmaf(st[8][0], SC2_, s0));
      st[8] = f32x4{w0, 0.f, 0.f, 0.f};
      ga[8] = f32x4{(g == 0) ? gk128 : 0.f, 0.f, 0.f, 0.f};
      psum += w0;
    }
    psum += __shfl_xor(psum, 16);
    psum += __shfl_xor(psum, 32);
    const float inv = __builtin_amdgcn_rcpf(psum);

    #pragma unroll
    for (int f = 0; f < 9; ++f) {
      const float c0 = fmaf(st[f][0], inv, ga[f][0]);
      const float c1 = fmaf(st[f][1], inv, ga[f][1]);
      const float c2 = fmaf(st[f][2], inv, ga[f][2]);
      const float c3 = fmaf(st[f][3], inv, ga[f][3]);
      uint2 pw;
      pw.x = (u32)ftobf16(c0) | ((u32)ftobf16(c1) << 16);
      pw.y = (u32)ftobf16(c2) | ((u32)ftobf16(c3) << 16);
      *(uint2*)(pb + ql * 336 + (16 * f + 4 * g) * 2) = pw;
    }
    f32x4 o0{0.f,0.f,0.f,0.f}, o1{0.f,0.f,0.f,0.f};
    #pragma unroll
    for (int c = 0; c < 5; ++c) {
      const bf16x8 pa = *(const bf16x8*)(pb + ql * 336 + (32 * c + 8 * g) * 2);
      o0 = __builtin_amdgcn_mfma_f32_16x16x32_bf16(pa, vf[c][0], o0, 0, 0, 0);
      o1 = __builtin_amdgcn_mfma_f32_16x16x32_bf16(pa, vf[c][1], o1, 0, 0, 0);
    }
    u16* aop;
    size_t ostr;
    if constexpr (INPLACE) {
      aop = qkv_blk + (size_t)(mt * 16 + g * 4) * 768 + 256 + h * 32 + ql;
      ostr = 768;
    } else {
      aop = ao + ((size_t)wgi * BS_ + mt * 16 + g * 4) * C_ + h * 32 + ql;
      ostr = C_;
    }
    #pragma unroll
    for (int r = 0; r < 4; ++r) {
      aop[r * ostr]      = ftobf16(o0[r]);
      aop[r * ostr + 16] = ftobf16(o1[r]);
    }
  }
}

extern "C" void kernel_launch(void* const* d_in, const int* in_sizes, int n_in,
                              void* d_out, int out_size, void* d_ws, size_t ws_size,
                              hipStream_t stream) {
  (void)in_sizes; (void)n_in; (void)out_size;
  const float* x      = (const float*)d_in[0];
  const int*   mask   = (const int*)  d_in[1];
  const float* ef     = (const float*)d_in[2];
  const float* w_qkv  = (const float*)d_in[3];
  const float* b_qkv  = (const float*)d_in[4];
  const float* w_proj = (const float*)d_in[5];
  const float* b_proj = (const float*)d_in[6];
  const float* w_gate = (const float*)d_in[7];
  const float* b_gate = (const float*)d_in[8];
  float* out = (float*)d_out;
  char* ws = (char*)d_ws;

  const bool bigws = (ws_size >= 152829952ull);

  // common buffers
  float* bn  = (float*)(ws);                 //       524,288
  u16*   qkv = (u16*)(ws + 524288);          //   101,449,728

  u16* ao; s16* wtq; s16* wtp; u16* e4t;
  if (bigws) {   // round-4-proven layout + e4t, total 152,829,952
    ao  = (u16*)(ws + 101974016);            //    33,554,432
    wtq = (s16*)(ws + 135528448);            //       393,216
    wtp = (s16*)(ws + 135921664);            //       131,072
    e4t = (u16*)(ws + 136052736);            //    16,777,216
  } else {       // compact in-place layout, total 119,275,520
    ao  = nullptr;
    wtq = (s16*)(ws + 101974016);
    wtp = (s16*)(ws + 102367232);
    e4t = (u16*)(ws + 102498304);
  }

  mean_kernel<<<B_ * NB_, 256, 0, stream>>>(x, bn);
  wt_kernel<<<(768 * 256 + 256 * 256) / 256, 256, 0, stream>>>(
      w_qkv, w_proj, wtq, wtp);
  pre_kernel<<<(NB_ * BS_ * 32) / 256, 256, 0, stream>>>(mask, ef, e4t);
  mfma_gemm<true, false, true, 768>
      <<<dim3((B_ * NB_ * KL_) / 128, 6), 256, 0, stream>>>(
      nullptr, x, bn, wtq, b_qkv, qkv);
  if (bigws) {
    attn_kernel<false><<<B_ * NB_ * 2, 256, 0, stream>>>(
        qkv, (const u16*)e4t, w_gate, b_gate, ao);
    mfma_gemm<false, false, false, 256>
        <<<dim3((B_ * NB_ * BS_) / 128, 2), 256, 0, stream>>>(
        (const s16*)ao, nullptr, nullptr, wtp, b_proj, out);
  } else {
    attn_kernel<true><<<B_ * NB_ * 2, 256, 0, stream>>>(
        qkv, (const u16*)e4t, w_gate, b_gate, nullptr);
    mfma_gemm<false, true, false, 256>
        <<<dim3((B_ * NB_ * BS_) / 128, 2), 256, 0, stream>>>(
        (const s16*)qkv, nullptr, nullptr, wtp, b_proj, out);
  }
}

// Round 8
// 230.314 us; speedup vs baseline: 11.0132x; 1.0366x over previous
//
#include <hip/hip_runtime.h>

#define B_   4
#define NB_  128
#define BS_  128
#define C_   256
#define H_   8
#define KL_  129   // BS_+1
#define SC2_   0.25503486f           // (1/sqrt(32)) * log2(e)
#define LOG2E_ 1.4426950408889634f
#define LN2_   0.6931471805599453f
#define RSTR_  99072                 // KL_*768: u16 stride of one block in qkv
#define WREG_  13056                 // per-wave LDS: V^T[32][136] + P[16][272B]

typedef unsigned short u16;
typedef unsigned int   u32;
typedef short          s16;
typedef __attribute__((ext_vector_type(8))) __bf16 bf16x8;
typedef __attribute__((ext_vector_type(4))) float  f32x4;

__device__ __forceinline__ float bf16tof(u16 u) {
  union { u32 i; float f; } v; v.i = ((u32)u) << 16; return v.f;
}
__device__ __forceinline__ u16 ftobf16(float f) {
  union { float f; u32 i; } v; v.f = f;
  u32 b = v.i + 0x7FFFu + ((v.i >> 16) & 1u);
  return (u16)(b >> 16);
}
__device__ __forceinline__ float asf(u32 u) {
  union { u32 i; float f; } v; v.i = u; return v.f;
}

__device__ __forceinline__ void glds16(const void* g, void* l) {
  __builtin_amdgcn_global_load_lds(
      (const __attribute__((address_space(1))) unsigned int*)g,
      (__attribute__((address_space(3))) unsigned int*)l, 16, 0, 0);
}

// ---------- kernel 1: fused per-block mean + f32->bf16 convert ----------
// xb[blk][r<128][c] = bf16(x[blk][r][c]); xb[blk][128][c] = bf16(mean_r x).
__global__ __launch_bounds__(256) void meancvt_kernel(const float* __restrict__ x,
                                                      u16* __restrict__ xb) {
  const int blk = blockIdx.x;
  const int c = threadIdx.x;
  const float* p = x + (size_t)blk * BS_ * C_ + c;
  u16* q = xb + (size_t)blk * (KL_ * C_) + c;
  float s = 0.f;
  #pragma unroll 4
  for (int r = 0; r < BS_; ++r) {
    const float v = p[(size_t)r * C_];
    s += v;
    q[(size_t)r * C_] = ftobf16(v);
  }
  q[(size_t)BS_ * C_] = ftobf16(s * (1.0f / BS_));
}

// ---------- kernel 2: transpose+convert weights ----------
__global__ __launch_bounds__(256) void wt_kernel(const float* __restrict__ wq,
      const float* __restrict__ wp, s16* __restrict__ wtq, s16* __restrict__ wtp) {
  const int i = blockIdx.x * 256 + threadIdx.x;
  if (i < 768 * 256) {
    const int nn = i >> 8, k = i & 255;
    wtq[i] = (s16)ftobf16(wq[k * 768 + nn]);
  } else {
    const int j = i - 768 * 256;
    const int nn = j >> 8, k = j & 255;
    wtp[j] = (s16)ftobf16(wp[k * 256 + nn]);
  }
}

// ---------- kernel 4: edge-bias precompute (runs AFTER qkv GEMM; aliases xb) -
// e4t[n][q][key<128] = 4 bf16 {e0, e1, e2, e3*log2e}; diag -> (0,0,0,log2e);
// masked -> (0,0,0,-1e30). Key 128 handled in attn (always unmasked).
__global__ __launch_bounds__(256) void pre_kernel(const int* __restrict__ mask,
      const float* __restrict__ ef, u16* __restrict__ e4t) {
  const int t = blockIdx.x * 256 + threadIdx.x;   // (n*128+q)*32 + kq
  const int kq = t & 31;
  const int row = t >> 5;                          // n*128+q
  const int q = row & 127;
  const int key0 = kq * 4;
  const int* mrow = mask + (size_t)row * KL_;
  const float* erow = ef + (size_t)row * KL_ * 4;
  u32 o[8];
  #pragma unroll
  for (int r = 0; r < 4; ++r) {
    const int key = key0 + r;
    const int m = mrow[key];
    float4 e = *(const float4*)(erow + (size_t)key * 4);
    if (key == q) { e.x = 0.f; e.y = 0.f; e.z = 0.f; e.w = 1.f; }
    float e3L = e.w * LOG2E_;
    if (!m) { e.x = 0.f; e.y = 0.f; e.z = 0.f; e3L = -1e30f; }
    o[2*r]   = (u32)ftobf16(e.x) | ((u32)ftobf16(e.y) << 16);
    o[2*r+1] = (u32)ftobf16(e.z) | ((u32)ftobf16(e3L) << 16);
  }
  uint4* dst = (uint4*)(e4t + (size_t)row * 512 + key0 * 4);
  dst[0] = uint4{o[0], o[1], o[2], o[3]};
  dst[1] = uint4{o[4], o[5], o[6], o[7]};
}

// ---------- kernels 3 & 6: MFMA bf16 GEMM, 2-phase double-buffered ----------
// C[M][NS] = A[M][256] @ Bt[NS][256]^T + bias.  row0 = by*128, col0 = bx*128
// (bx fastest -> consecutive WGs share the A panel in L2/L3).
// STRIDED: A bf16 from qkv K-plane: row -> qkv + by*RSTR_ + row*768 + 256.
template<bool STRIDED, bool OBF16, int NS>
__global__ __launch_bounds__(256) void mfma_gemm(const s16* __restrict__ Ab,
      const s16* __restrict__ Bt, const float* __restrict__ bias,
      void* __restrict__ outv) {
  __shared__ __align__(16) s16 Al[2][128 * 64];
  __shared__ __align__(16) s16 Bl[2][128 * 64];
  const int tid = threadIdx.x;
  const int lane = tid & 63;
  const int wid = tid >> 6;
  const int row0 = blockIdx.y * 128;
  const int col0 = blockIdx.x * 128;
  const int ldrow = lane >> 3;
  const int lcb   = (lane & 7) * 16;

  auto STAGE = [&](int k0, int buf) {
    #pragma unroll
    for (int j = 0; j < 4; ++j) {
      const int c = wid * 4 + j;
      const int row = c * 8 + ldrow;
      const int scb = lcb ^ ((row & 7) << 4);
      glds16(Bt + (size_t)(col0 + row) * C_ + k0 + (scb >> 1), &Bl[buf][c * 512]);
    }
    #pragma unroll
    for (int j = 0; j < 4; ++j) {
      const int c = wid * 4 + j;
      const int row = c * 8 + ldrow;
      const int scb = lcb ^ ((row & 7) << 4);
      if constexpr (STRIDED)
        glds16(Ab + (size_t)blockIdx.y * RSTR_ + (size_t)row * 768 + 256
                  + k0 + (scb >> 1), &Al[buf][c * 512]);
      else
        glds16(Ab + (size_t)(row0 + row) * C_ + k0 + (scb >> 1), &Al[buf][c * 512]);
    }
  };

  f32x4 acc[4][4];
  #pragma unroll
  for (int i = 0; i < 4; ++i)
    #pragma unroll
    for (int j = 0; j < 4; ++j) acc[i][j] = f32x4{0.f, 0.f, 0.f, 0.f};

  STAGE(0, 0);
  __syncthreads();

  const int fr = lane & 15;
  const int ar0 = (wid >> 1) * 64;
  const int ac0 = (wid & 1) * 64;
  #pragma unroll 1
  for (int t = 0; t < 4; ++t) {
    if (t < 3) STAGE((t + 1) * 64, (t + 1) & 1);   // prefetch next K-step
    const char* Ac = (const char*)&Al[t & 1][0];
    const char* Bc = (const char*)&Bl[t & 1][0];
    #pragma unroll
    for (int kk = 0; kk < 64; kk += 32) {
      const int kb = kk * 2 + (lane >> 4) * 16;
      bf16x8 af[4], bfr[4];
      #pragma unroll
      for (int mf = 0; mf < 4; ++mf) {
        const int row = ar0 + mf * 16 + fr;
        af[mf] = *(const bf16x8*)(Ac + row * 128 + (kb ^ ((row & 7) << 4)));
      }
      #pragma unroll
      for (int nf = 0; nf < 4; ++nf) {
        const int row = ac0 + nf * 16 + fr;
        bfr[nf] = *(const bf16x8*)(Bc + row * 128 + (kb ^ ((row & 7) << 4)));
      }
      #pragma unroll
      for (int mf = 0; mf < 4; ++mf)
        #pragma unroll
        for (int nf = 0; nf < 4; ++nf)
          acc[mf][nf] = __builtin_amdgcn_mfma_f32_16x16x32_bf16(
              af[mf], bfr[nf], acc[mf][nf], 0, 0, 0);
    }
    __syncthreads();   // drains prefetch (vmcnt) + protects buffer reuse
  }

  const int orow0 = row0 + (wid >> 1) * 64 + (lane >> 4) * 4;
  const int ocol0 = col0 + (wid & 1) * 64 + (lane & 15);
  #pragma unroll
  for (int nf = 0; nf < 4; ++nf) {
    const int col = ocol0 + nf * 16;
    const float bb = bias[col];
    #pragma unroll
    for (int mf = 0; mf < 4; ++mf) {
      #pragma unroll
      for (int r = 0; r < 4; ++r) {
        const size_t row = (size_t)(orow0 + mf * 16 + r);
        const float v = acc[mf][nf][r] + bb;
        if constexpr (OBF16) ((u16*)outv)[row * NS + col] = ftobf16(v);
        else                 ((float*)outv)[row * NS + col] = v;
      }
    }
  }
}

// ---------- kernel 5: MFMA fused block attention ----------
// Grid (b*NB+n)*2+hg; wave wid -> head hg*4+wid; no cross-wave LDS sharing.
// V^T[32][136] holds keys 0..127 only; key-128 contribution added as a
// rank-1 shuffle-FMA (kills PV chunk 4 and ALL pad reads). 3 WG/CU.
// Output written in-place into the K-plane of qkv (disjoint head columns;
// this wave's K fragments are register-resident before any write).
__global__ __launch_bounds__(256, 3) void attn_kernel(u16* __restrict__ qkv,
      const u16* __restrict__ e4t, const float* __restrict__ wg_,
      const float* __restrict__ bg) {
  __shared__ __align__(16) char lds[4 * WREG_];   // 52224 B
  const int bid = blockIdx.x;
  const int wgi = bid >> 1;
  const int hg  = bid & 1;
  const int n = wgi & (NB_ - 1);
  const int tid = threadIdx.x;
  const int wid = tid >> 6, lane = tid & 63;
  const int h = hg * 4 + wid;
  const int g = lane >> 4, ql = lane & 15;
  char* wbase = lds + wid * WREG_;
  u16* vt = (u16*)wbase;               // [32 d][136 keys] bf16
  char* pb = wbase + 8704;             // 16 q-rows x 272 B

  u16* qkv_blk = qkv + (size_t)wgi * RSTR_;
  const u16* ebase = e4t + (size_t)n * (128 * 512);

  // stage V^T for keys 0..127 (transposed; every byte later read is written)
  #pragma unroll
  for (int it = 0; it < 8; ++it) {
    const int idx = it * 64 + lane;          // 0..511
    const int r = idx >> 2, dc = idx & 3;
    const uint4 u = *(const uint4*)(qkv_blk + (size_t)r * 768 + 512 + h * 32 + dc * 8);
    u16* col = vt + (dc * 8) * 136 + r;
    col[0 * 136] = (u16)(u.x & 0xffff); col[1 * 136] = (u16)(u.x >> 16);
    col[2 * 136] = (u16)(u.y & 0xffff); col[3 * 136] = (u16)(u.y >> 16);
    col[4 * 136] = (u16)(u.z & 0xffff); col[5 * 136] = (u16)(u.z >> 16);
    col[6 * 136] = (u16)(u.w & 0xffff); col[7 * 136] = (u16)(u.w >> 16);
  }

  // K frags (A-operand); f=8 rows clamped to 128 (dups masked to w=0)
  bf16x8 kf[9];
  #pragma unroll
  for (int f = 0; f < 9; ++f) {
    int kr = 16 * f + ql; if (kr > 128) kr = 128;
    kf[f] = *(const bf16x8*)(qkv_blk + (size_t)kr * 768 + 256 + h * 32 + g * 8);
  }
  // V frags (B-operand) for keys 0..127
  bf16x8 vf[4][2];
  #pragma unroll
  for (int c = 0; c < 4; ++c)
    #pragma unroll
    for (int nf = 0; nf < 2; ++nf)
      vf[c][nf] = *(const bf16x8*)(vt + (nf * 16 + ql) * 136 + 32 * c + 8 * g);
  // key-128 V values for this lane's two output columns
  const float v128a = bf16tof(qkv_blk[(size_t)128 * 768 + 512 + h * 32 + ql]);
  const float v128b = bf16tof(qkv_blk[(size_t)128 * 768 + 512 + h * 32 + 16 + ql]);

  const float wgc0 = wg_[h], wgc1 = wg_[8 + h], wgc2 = wg_[16 + h];
  const float wgc3s = wg_[24 + h] * LN2_;   // pairs with e3*log2e
  const float bgh = bg[h];
  const float gk128 = wg_[24 + h] + bgh;

  #pragma unroll 1
  for (int mt = 0; mt < 8; ++mt) {
    const int qrow = mt * 16 + ql;
    const bf16x8 qf = *(const bf16x8*)(qkv_blk + (size_t)qrow * 768 + h * 32 + g * 8);
    const uint4* eql = (const uint4*)(ebase + (size_t)qrow * 512) + 2 * g;

    f32x4 st[9], ga[8];
    #pragma unroll
    for (int f = 0; f < 9; ++f)
      st[f] = __builtin_amdgcn_mfma_f32_16x16x32_bf16(
          kf[f], qf, f32x4{0.f, 0.f, 0.f, 0.f}, 0, 0, 0);

    float psum = 0.f;
    #pragma unroll
    for (int f = 0; f < 8; ++f) {
      const uint4 ea = eql[8 * f];
      const uint4 eb = eql[8 * f + 1];
      const u32 wa[4] = {ea.x, ea.z, eb.x, eb.z};
      const u32 wb[4] = {ea.y, ea.w, eb.y, eb.w};
      #pragma unroll
      for (int r = 0; r < 4; ++r) {
        const float e0 = asf(wa[r] << 16), e1 = asf(wa[r] & 0xffff0000u);
        const float e2 = asf(wb[r] << 16), e3L = asf(wb[r] & 0xffff0000u);
        const float gg = fmaf(e0, wgc0, fmaf(e1, wgc1,
                          fmaf(e2, wgc2, fmaf(e3L, wgc3s, bgh))));
        ga[f][r] = (e3L > -1e29f) ? gg : 0.f;
        const float w = __builtin_amdgcn_exp2f(fmaf(st[f][r], SC2_, e3L));
        st[f][r] = w;
        psum += w;
      }
    }
    // key 128 (always unmasked); st[8][0] = S[128][qrow] on g==0 lanes
    const float w0 = __builtin_amdgcn_exp2f(
        fmaf(st[8][0], SC2_, (g == 0) ? LOG2E_ : -1e30f));
    psum += w0;
    psum += __shfl_xor(psum, 16);
    psum += __shfl_xor(psum, 32);
    const float inv = __builtin_amdgcn_rcpf(psum);
    const float c128 = fmaf(w0, inv, (g == 0) ? gk128 : 0.f);

    #pragma unroll
    for (int f = 0; f < 8; ++f) {
      uint2 pw;
      pw.x = (u32)ftobf16(fmaf(st[f][0], inv, ga[f][0]))
           | ((u32)ftobf16(fmaf(st[f][1], inv, ga[f][1])) << 16);
      pw.y = (u32)ftobf16(fmaf(st[f][2], inv, ga[f][2]))
           | ((u32)ftobf16(fmaf(st[f][3], inv, ga[f][3])) << 16);
      *(uint2*)(pb + ql * 272 + (16 * f + 4 * g) * 2) = pw;
    }
    f32x4 o0{0.f,0.f,0.f,0.f}, o1{0.f,0.f,0.f,0.f};
    #pragma unroll
    for (int c = 0; c < 4; ++c) {
      const bf16x8 pa = *(const bf16x8*)(pb + ql * 272 + (32 * c + 8 * g) * 2);
      o0 = __builtin_amdgcn_mfma_f32_16x16x32_bf16(pa, vf[c][0], o0, 0, 0, 0);
      o1 = __builtin_amdgcn_mfma_f32_16x16x32_bf16(pa, vf[c][1], o1, 0, 0, 0);
    }
    // add key-128 rank-1 term and store into K-plane
    u16* aop = qkv_blk + (size_t)(mt * 16 + g * 4) * 768 + 256 + h * 32 + ql;
    #pragma unroll
    for (int r = 0; r < 4; ++r) {
      const float cc = __shfl(c128, 4 * g + r);   // c128 of q-row mt*16+4g+r
      aop[(size_t)r * 768]      = ftobf16(fmaf(cc, v128a, o0[r]));
      aop[(size_t)r * 768 + 16] = ftobf16(fmaf(cc, v128b, o1[r]));
    }
  }
}

extern "C" void kernel_launch(void* const* d_in, const int* in_sizes, int n_in,
                              void* d_out, int out_size, void* d_ws, size_t ws_size,
                              hipStream_t stream) {
  (void)in_sizes; (void)n_in; (void)out_size; (void)ws_size;
  const float* x      = (const float*)d_in[0];
  const int*   mask   = (const int*)  d_in[1];
  const float* ef     = (const float*)d_in[2];
  const float* w_qkv  = (const float*)d_in[3];
  const float* b_qkv  = (const float*)d_in[4];
  const float* w_proj = (const float*)d_in[5];
  const float* b_proj = (const float*)d_in[6];
  const float* w_gate = (const float*)d_in[7];
  const float* b_gate = (const float*)d_in[8];
  float* out = (float*)d_out;
  char* ws = (char*)d_ws;

  // workspace layout (bytes), total 135,790,592 (<= proven 136,052,736)
  u16* qkv = (u16*)(ws);                     //   101,449,728
  s16* wtq = (s16*)(ws + 101449728);         //       393,216
  s16* wtp = (s16*)(ws + 101842944);         //       131,072
  u16* xb  = (u16*)(ws + 101974016);         //    33,816,576 (dead after QKV GEMM)
  u16* e4t = (u16*)(ws + 101974016);         //    16,777,216 (aliases xb; written after)

  meancvt_kernel<<<B_ * NB_, 256, 0, stream>>>(x, xb);
  wt_kernel<<<(768 * 256 + 256 * 256) / 256, 256, 0, stream>>>(
      w_qkv, w_proj, wtq, wtp);
  mfma_gemm<false, true, 768>
      <<<dim3(6, (B_ * NB_ * KL_) / 128), 256, 0, stream>>>(
      (const s16*)xb, wtq, b_qkv, qkv);
  pre_kernel<<<(NB_ * BS_ * 32) / 256, 256, 0, stream>>>(mask, ef, e4t);
  attn_kernel<<<B_ * NB_ * 2, 256, 0, stream>>>(
      qkv, (const u16*)e4t, w_gate, b_gate);
  mfma_gemm<true, false, 256>
      <<<dim3(2, (B_ * NB_ * BS_) / 128), 256, 0, stream>>>(
      (const s16*)qkv, wtp, b_proj, out);
}